// Round 6
// baseline (1042.496 us; speedup 1.0000x reference)
//
#include <hip/hip_runtime.h>

#define SEQ 8192
#define DIM 768

typedef __attribute__((ext_vector_type(8))) short s16x8;   // 8 x bf16
typedef __attribute__((ext_vector_type(4))) float f32x4;

// RNE float -> bf16
__device__ __forceinline__ unsigned short f2bf(float f) {
  union { float f; unsigned u; } v; v.f = f;
  unsigned r = v.u + 0x7FFFu + ((v.u >> 16) & 1u);
  return (unsigned short)(r >> 16);
}

__device__ __forceinline__ float bf2f(unsigned short s) {
  union { unsigned u; float f; } v; v.u = ((unsigned)s) << 16;
  return v.f;
}

// async global->LDS 16B copy: lds dest = wave-uniform base + lane*16
__device__ __forceinline__ void gll16(const void* gsrc, void* ldst) {
  __builtin_amdgcn_global_load_lds(
      (__attribute__((address_space(1))) unsigned int*)gsrc,
      (__attribute__((address_space(3))) unsigned int*)ldst, 16, 0, 0);
}

// ---------------- fused cast kernel: x (6144 blocks) + wq/wk/wv (576 each) ----------------
#define XN4 (SEQ * DIM / 4)     // 1572864
#define WN4 (DIM * DIM / 4)     // 147456

__global__ void cast_all_kernel(const float* __restrict__ x, const float* __restrict__ wq,
                                const float* __restrict__ wk, const float* __restrict__ wv,
                                unsigned short* __restrict__ dx, unsigned short* __restrict__ dq,
                                unsigned short* __restrict__ dk, unsigned short* __restrict__ dv) {
  int i = blockIdx.x * blockDim.x + threadIdx.x;
  const float* s;
  unsigned short* d;
  int off;
  if (i < XN4) {
    s = x; d = dx; off = i;
  } else {
    int j = i - XN4;
    int wi = j / WN4;
    off = j - wi * WN4;
    s = (wi == 0) ? wq : ((wi == 1) ? wk : wv);
    d = (wi == 0) ? dq : ((wi == 1) ? dk : dv);
  }
  float4 v = ((const float4*)s)[off];
  ushort4 r; r.x = f2bf(v.x); r.y = f2bf(v.y); r.z = f2bf(v.z); r.w = f2bf(v.w);
  ((ushort4*)d)[off] = r;
}

// ---------------- projection GEMM: C[m][n] = sum_k X[m][k]*W[n][k] ----------------
// z==2 writes V in key-blocked layout: Vt_blk[key>>5][vr 768][key&31]
__global__ __launch_bounds__(256, 2)
void proj_kernel(const unsigned short* __restrict__ X,
                 const unsigned short* __restrict__ Wq,
                 const unsigned short* __restrict__ Wk,
                 const unsigned short* __restrict__ Wv,
                 unsigned short* __restrict__ Qb,
                 unsigned short* __restrict__ Kb,
                 unsigned short* __restrict__ Vtb) {
  __shared__ __align__(16) char lds[65536];
  const int tid = threadIdx.x;
  const int lane = tid & 63, wv = tid >> 6;
  const int l15 = lane & 15, l4 = lane >> 4;
  const int mt = blockIdx.x, nt = blockIdx.y, z = blockIdx.z;
  const unsigned short* W = (z == 0) ? Wq : ((z == 1) ? Wk : Wv);

  f32x4 acc[4][4];
#pragma unroll
  for (int i = 0; i < 4; ++i)
#pragma unroll
    for (int j = 0; j < 4; ++j) acc[i][j] = f32x4{0.f, 0.f, 0.f, 0.f};

  auto stage = [&](int kk) {
    char* At = lds + (kk & 1) * 32768;
    char* Bt = At + 16384;
    const int d0 = kk * 64;
#pragma unroll
    for (int i = 0; i < 4; ++i) {
      int s = i * 256 + tid;
      int row = s >> 3, c = (s & 7) ^ (row & 7);
      gll16(X + (long)(mt * 128 + row) * DIM + d0 + c * 8, At + i * 4096 + (wv << 10));
      gll16(W + (long)(nt * 128 + row) * DIM + d0 + c * 8, Bt + i * 4096 + (wv << 10));
    }
  };

  stage(0);
#pragma unroll 1
  for (int kk = 0; kk < 12; ++kk) {
    __syncthreads();
    if (kk + 1 < 12) stage(kk + 1);
    const char* At = lds + (kk & 1) * 32768;
    const char* Bt = At + 16384;
#pragma unroll
    for (int ks = 0; ks < 2; ++ks) {
      const int c = ks * 4 + l4;
      s16x8 a[4], b[4];
#pragma unroll
      for (int mi = 0; mi < 4; ++mi) {
        int row = (wv & 1) * 64 + mi * 16 + l15;
        a[mi] = *(const s16x8*)(At + row * 128 + ((c ^ (row & 7)) << 4));
      }
#pragma unroll
      for (int ni = 0; ni < 4; ++ni) {
        int row = (wv >> 1) * 64 + ni * 16 + l15;
        b[ni] = *(const s16x8*)(Bt + row * 128 + ((c ^ (row & 7)) << 4));
      }
#pragma unroll
      for (int mi = 0; mi < 4; ++mi)
#pragma unroll
        for (int ni = 0; ni < 4; ++ni)
          acc[mi][ni] = __builtin_amdgcn_mfma_f32_16x16x32_bf16(a[mi], b[ni], acc[mi][ni], 0, 0, 0);
    }
  }

#pragma unroll
  for (int mi = 0; mi < 4; ++mi)
#pragma unroll
    for (int ni = 0; ni < 4; ++ni) {
      int row0 = mt * 128 + (wv & 1) * 64 + mi * 16 + l4 * 4;
      int col = nt * 128 + (wv >> 1) * 64 + ni * 16 + l15;
      if (z == 2) {
        ushort4 r;
        r.x = f2bf(acc[mi][ni][0]); r.y = f2bf(acc[mi][ni][1]);
        r.z = f2bf(acc[mi][ni][2]); r.w = f2bf(acc[mi][ni][3]);
        // blocked: [row0>>5][col][row0&31]; keys row0..row0+3 stay in one 32-block
        *(ushort4*)(Vtb + (long)(row0 >> 5) * (DIM * 32) + col * 32 + (row0 & 31)) = r;
      } else {
        unsigned short* dst = (z == 0) ? Qb : Kb;
#pragma unroll
        for (int g = 0; g < 4; ++g)
          dst[(long)(row0 + g) * DIM + col] = f2bf(acc[mi][ni][g]);
      }
    }
}

// ---------------- flash attention: BM=128, 16 waves, 160KB LDS, 1 block/CU ----------------
// 1024 threads (16 waves, 4/SIMD). BN=256 keys/iter. All 16x16x32 MFMA.
// Per-wave read/MFMA profile identical to the 281us R4 kernel; barriers HALVED
// (20/iter x 8 iters vs 20 x 16) and 2x waves/SIMD hide ds_read + drain latency.
// LDS (163840 B): arena = two 48KB slots S0=[0,49152) S1=[49152,98304);
//   QK round r: buf r&1 (Q 16KB @ +0, K 32KB @ +16384), 128B rows, XOR-(row&7).
//   PV chunk v (32 keys x full 768 vr, 48KB): slot v&1, 64B rows, c^((vr>>1)&3).
//   P = [98304,163840): 128x256 bf16, swizzled. l_part aliases lds[0,2048) post-loop.
// Slot audit: QK r reads buf r&1, stages buf (r+1)&1; r=11 (reads S1) stages V
//   chunk0 -> S0. PV v reads slot v&1, stages slot (v+1)&1; v=7 (reads S1) stages
//   next-iter QK(0) -> S0. Every dest's last reader >=1 barrier behind.
// QK wave map: Rq=wv&3 (32-row group), Cq=wv>>2 (64-key group).
// PV wave map: rh=wv&1 (64-row half), dc=wv>>1 (96-d group).
#define SCALE_LOG2E 0.05205878f  // (1/sqrt(768)) * log2(e)

__global__ __launch_bounds__(1024, 4)
void flash_kernel(const unsigned short* __restrict__ Q,   // [8192][768] bf16
                  const unsigned short* __restrict__ K,   // [8192][768] bf16
                  const unsigned short* __restrict__ V,   // blocked Vt [256][768][32] bf16
                  unsigned short* __restrict__ partp,     // [G][8192][768] bf16 (G-split mode)
                  float* __restrict__ outf,               // [8192][768] fp32 (norm mode)
                  float* __restrict__ lout,               // [G][8192] (G-split mode)
                  int kv_len, int norm_out) {
  __shared__ __align__(16) char lds[163840];
  char* Pl = lds + 98304;
  float* l_part = (float*)lds;  // [4][128], used only after the main loop

  const int tid = threadIdx.x;
  const int lane = tid & 63, wv = tid >> 6;
  const int l15 = lane & 15, l4 = lane >> 4;
  const int qtile = blockIdx.x, split = blockIdx.y;
  const long kv0 = (long)split * kv_len;
  const long qrow0 = (long)qtile * 128;
  const int Rq = wv & 3, Cq = wv >> 2;   // QK: S row-group / key-group
  const int rh = wv & 1, dc = wv >> 1;   // PV: O row-half / d-group

  f32x4 acc_o[4][6];
  float acc_lp[8];
#pragma unroll
  for (int i = 0; i < 4; ++i)
#pragma unroll
    for (int j = 0; j < 6; ++j) acc_o[i][j] = f32x4{0.f, 0.f, 0.f, 0.f};
#pragma unroll
  for (int i = 0; i < 8; ++i) acc_lp[i] = 0.f;

  const int niter = kv_len >> 8;

  // QK stage: round r covers dims [r*64, r*64+64). Q 16KB + K 32KB, 128B rows.
  auto stageQK = [&](int r, long kbase) {
    char* buf = lds + (r & 1) * 49152;
    char* Qc = buf;
    char* Kc = buf + 16384;
    const int d0 = r * 64;
    {
      int s = tid;                      // 1024 slots = 16KB
      int row = s >> 3, c = (s & 7) ^ (row & 7);
      gll16(Q + (qrow0 + row) * DIM + d0 + c * 8, Qc + (wv << 10));
    }
#pragma unroll
    for (int i = 0; i < 2; ++i) {
      int s = i * 1024 + tid;           // 2048 slots = 32KB
      int row = s >> 3, c = (s & 7) ^ (row & 7);
      gll16(K + (kbase + row) * DIM + d0 + c * 8, Kc + i * 16384 + (wv << 10));
    }
  };

  // PV stage: chunk v = key-block (32 keys) x full 768 vr = 48KB. 64B rows.
  auto stagePV = [&](int v, long kblk0) {
    char* Vc = lds + (v & 1) * 49152;
    const long blkbase = (kblk0 + v) * (long)(DIM * 32);
#pragma unroll
    for (int i = 0; i < 3; ++i) {
      int s = i * 1024 + tid;           // 3072 slots = 48KB
      int vr = s >> 2, p = s & 3;
      int c = p ^ ((vr >> 1) & 3);
      gll16(V + blkbase + (long)vr * 32 + c * 8, Vc + i * 16384 + (wv << 10));
    }
  };

  stageQK(0, kv0);
#pragma unroll 1
  for (int it = 0; it < niter; ++it) {
    const long kb = kv0 + (long)it * 256;
    const long kblk0 = kb >> 5;

    // ---- QK: S[128x256], per-wave region [32 rows x 64 keys] = 2x4 16x16 tiles ----
    f32x4 acc_s[2][4];
#pragma unroll
    for (int a = 0; a < 2; ++a)
#pragma unroll
      for (int b = 0; b < 4; ++b) acc_s[a][b] = f32x4{0.f, 0.f, 0.f, 0.f};

#pragma unroll 1
    for (int r = 0; r < 12; ++r) {
      __syncthreads();  // drains stage(r); all waves done with prior compute
      if (r + 1 < 12) stageQK(r + 1, kb);
      else stagePV(0, kblk0);  // dest S0; r=11 reads S1 -> disjoint
      const char* buf = lds + (r & 1) * 49152;
      const char* Qc = buf;
      const char* Kc = buf + 16384;
#pragma unroll
      for (int ks = 0; ks < 2; ++ks) {
        const int c = ks * 4 + l4;
        s16x8 af[2], bk[4];
#pragma unroll
        for (int rt = 0; rt < 2; ++rt) {
          int row = Rq * 32 + rt * 16 + l15;
          af[rt] = *(const s16x8*)(Qc + row * 128 + ((c ^ (row & 7)) << 4));
        }
#pragma unroll
        for (int ct = 0; ct < 4; ++ct) {
          int kr = Cq * 64 + ct * 16 + l15;
          bk[ct] = *(const s16x8*)(Kc + kr * 128 + ((c ^ (kr & 7)) << 4));
        }
#pragma unroll
        for (int rt = 0; rt < 2; ++rt)
#pragma unroll
          for (int ct = 0; ct < 4; ++ct)
            acc_s[rt][ct] = __builtin_amdgcn_mfma_f32_16x16x32_bf16(af[rt], bk[ct], acc_s[rt][ct], 0, 0, 0);
      }
    }

    // ---- P = exp(S/sqrt(D)) -> bf16 -> LDS (swizzled [128][256]); l partials ----
#pragma unroll
    for (int rt = 0; rt < 2; ++rt)
#pragma unroll
      for (int ct = 0; ct < 4; ++ct)
#pragma unroll
        for (int g = 0; g < 4; ++g) {
          float p = exp2f(acc_s[rt][ct][g] * SCALE_LOG2E);
          acc_lp[rt * 4 + g] += p;
          int row = Rq * 32 + rt * 16 + l4 * 4 + g;
          int col = Cq * 64 + ct * 16 + l15;
          int off = row * 512 + ((((col >> 3) ^ (row & 7))) << 4) + ((col & 7) << 1);
          *(unsigned short*)(Pl + off) = f2bf(p);
        }

    // ---- PV: O[128x768] += P[128x256] @ V; 8 chunks of 32 keys x full 768 d ----
#pragma unroll 1
    for (int v = 0; v < 8; ++v) {
      __syncthreads();  // drains stage(v) (+P ds_writes at v=0); prev readers done
      if (v + 1 < 8) stagePV(v + 1, kblk0);
      else if (it + 1 < niter) stageQK(0, kb + 256);  // dest S0; v=7 reads S1
      const char* Vc = lds + (v & 1) * 49152;
      s16x8 pa[4];
      const int ck = v * 4 + l4;
#pragma unroll
      for (int rs = 0; rs < 4; ++rs) {
        int row = rh * 64 + rs * 16 + l15;
        int pc = (ck & ~7) | ((ck & 7) ^ (row & 7));
        pa[rs] = *(const s16x8*)(Pl + row * 512 + (pc << 4));
      }
#pragma unroll
      for (int j = 0; j < 6; ++j) {
        int vr = dc * 96 + j * 16 + l15;
        s16x8 vb = *(const s16x8*)(Vc + vr * 64 + ((l4 ^ ((vr >> 1) & 3)) << 4));
#pragma unroll
        for (int rs = 0; rs < 4; ++rs)
          acc_o[rs][j] =
              __builtin_amdgcn_mfma_f32_16x16x32_bf16(pa[rs], vb, acc_o[rs][j], 0, 0, 0);
      }
    }
  }

  // ---- l reduction: butterfly over lane bits 0..3 (16 cols/group), combine quarters ----
#pragma unroll
  for (int i = 0; i < 8; ++i) {
    float v = acc_lp[i];
    v += __shfl_xor(v, 1); v += __shfl_xor(v, 2);
    v += __shfl_xor(v, 4); v += __shfl_xor(v, 8);
    acc_lp[i] = v;
  }
  __syncthreads();  // all staging/reads done before l_part alias use
  if (l15 == 0) {
#pragma unroll
    for (int rt = 0; rt < 2; ++rt)
#pragma unroll
      for (int g = 0; g < 4; ++g)
        l_part[Cq * 128 + Rq * 32 + rt * 16 + l4 * 4 + g] = acc_lp[rt * 4 + g];
  }
  __syncthreads();

  if (!norm_out) {
    if (tid < 128)
      lout[(long)split * SEQ + qrow0 + tid] =
          l_part[tid] + l_part[128 + tid] + l_part[256 + tid] + l_part[384 + tid];
#pragma unroll
    for (int rs = 0; rs < 4; ++rs) {
      int row = rh * 64 + rs * 16 + l4 * 4;
#pragma unroll
      for (int j = 0; j < 6; ++j) {
        int col = dc * 96 + j * 16 + l15;
#pragma unroll
        for (int g = 0; g < 4; ++g)
          partp[(long)split * SEQ * DIM + (qrow0 + row + g) * DIM + col] = f2bf(acc_o[rs][j][g]);
      }
    }
  } else {
    float linv[4][4];
#pragma unroll
    for (int rs = 0; rs < 4; ++rs)
#pragma unroll
      for (int g = 0; g < 4; ++g) {
        int row = rh * 64 + rs * 16 + l4 * 4 + g;
        linv[rs][g] = 1.0f / (l_part[row] + l_part[128 + row] + l_part[256 + row] + l_part[384 + row]);
      }
#pragma unroll
    for (int rs = 0; rs < 4; ++rs) {
      int row = rh * 64 + rs * 16 + l4 * 4;
#pragma unroll
      for (int j = 0; j < 6; ++j) {
        int col = dc * 96 + j * 16 + l15;
#pragma unroll
        for (int g = 0; g < 4; ++g)
          outf[(qrow0 + row + g) * DIM + col] = acc_o[rs][j][g] * linv[rs][g];
      }
    }
  }
}

// ---------------- combine (G splits): out = (sum p_g) / (sum l_g), partials bf16 ----------------
__global__ void combine_kernel(const unsigned short* __restrict__ part,
                               const float* __restrict__ lsum,
                               float* __restrict__ out, int n4, int nsplit) {
  int i = blockIdx.x * blockDim.x + threadIdx.x;
  if (i >= n4) return;
  int row = (i * 4) / DIM;
  float4 o = {0.f, 0.f, 0.f, 0.f};
  float l = 0.f;
#pragma unroll 4
  for (int g = 0; g < nsplit; ++g) {
    ushort4 p = ((const ushort4*)(part + (long)g * SEQ * DIM))[i];
    o.x += bf2f(p.x); o.y += bf2f(p.y); o.z += bf2f(p.z); o.w += bf2f(p.w);
    l += lsum[(long)g * SEQ + row];
  }
  float inv = 1.0f / l;
  o.x *= inv; o.y *= inv; o.z *= inv; o.w *= inv;
  ((float4*)out)[i] = o;
}

// ---------------- host ----------------
extern "C" void kernel_launch(void* const* d_in, const int* in_sizes, int n_in,
                              void* d_out, int out_size, void* d_ws, size_t ws_size,
                              hipStream_t stream) {
  const float* x = (const float*)d_in[0];
  const float* wq = (const float*)d_in[1];
  const float* wk = (const float*)d_in[2];
  const float* wv = (const float*)d_in[3];
  float* out = (float*)d_out;
  char* ws = (char*)d_ws;

  const size_t o_xbf = 0;
  const size_t o_wq = o_xbf + (size_t)SEQ * DIM * 2;
  const size_t o_wk = o_wq + (size_t)DIM * DIM * 2;
  const size_t o_wv = o_wk + (size_t)DIM * DIM * 2;
  const size_t o_q = o_wv + (size_t)DIM * DIM * 2;
  const size_t o_k = o_q + (size_t)SEQ * DIM * 2;
  const size_t o_vt = o_k + (size_t)SEQ * DIM * 2;
  const size_t o_part = o_vt + (size_t)SEQ * DIM * 2;
  const size_t o_l4 = o_part + (size_t)4 * SEQ * DIM * 2;
  const size_t total_g4 = o_l4 + (size_t)4 * SEQ * 4;
  const size_t o_l2 = o_part + (size_t)2 * SEQ * DIM * 2;
  const size_t total_g2 = o_l2 + (size_t)2 * SEQ * 4;

  unsigned short* Xbf = (unsigned short*)(ws + o_xbf);
  unsigned short* Wqb = (unsigned short*)(ws + o_wq);
  unsigned short* Wkb = (unsigned short*)(ws + o_wk);
  unsigned short* Wvb = (unsigned short*)(ws + o_wv);
  unsigned short* Qb = (unsigned short*)(ws + o_q);
  unsigned short* Kb = (unsigned short*)(ws + o_k);
  unsigned short* Vtb = (unsigned short*)(ws + o_vt);
  unsigned short* part = (unsigned short*)(ws + o_part);

  int G;
  size_t o_l;
  if (ws_size >= total_g4) { G = 4; o_l = o_l4; }
  else if (ws_size >= total_g2) { G = 2; o_l = o_l2; }
  else { G = 1; o_l = o_part; }
  float* lbuf = (float*)(ws + o_l);

  cast_all_kernel<<<7872, 256, 0, stream>>>(x, wq, wk, wv, Xbf, Wqb, Wkb, Wvb);
  proj_kernel<<<dim3(64, 6, 3), 256, 0, stream>>>(Xbf, Wqb, Wkb, Wvb, Qb, Kb, Vtb);
  if (G > 1) {
    flash_kernel<<<dim3(64, G), 1024, 0, stream>>>(Qb, Kb, Vtb, part, nullptr, lbuf, SEQ / G, 0);
    combine_kernel<<<6144, 256, 0, stream>>>(part, lbuf, out, SEQ * DIM / 4, G);
  } else {
    flash_kernel<<<dim3(64, 1), 1024, 0, stream>>>(Qb, Kb, Vtb, nullptr, out, nullptr, SEQ, 1);
  }
}

// Round 8
// 465.205 us; speedup vs baseline: 2.2409x; 2.2409x over previous
//
#include <hip/hip_runtime.h>

#define SEQ 8192
#define DIM 768

typedef __attribute__((ext_vector_type(8))) short s16x8;   // 8 x bf16
typedef __attribute__((ext_vector_type(4))) float f32x4;

// RNE float -> bf16
__device__ __forceinline__ unsigned short f2bf(float f) {
  union { float f; unsigned u; } v; v.f = f;
  unsigned r = v.u + 0x7FFFu + ((v.u >> 16) & 1u);
  return (unsigned short)(r >> 16);
}

__device__ __forceinline__ float bf2f(unsigned short s) {
  union { unsigned u; float f; } v; v.u = ((unsigned)s) << 16;
  return v.f;
}

// async global->LDS 16B copy: lds dest = wave-uniform base + lane*16
__device__ __forceinline__ void gll16(const void* gsrc, void* ldst) {
  __builtin_amdgcn_global_load_lds(
      (__attribute__((address_space(1))) unsigned int*)gsrc,
      (__attribute__((address_space(3))) unsigned int*)ldst, 16, 0, 0);
}

// ---------------- fused cast kernel: x (6144 blocks) + wq/wk/wv (576 each) ----------------
#define XN4 (SEQ * DIM / 4)     // 1572864
#define WN4 (DIM * DIM / 4)     // 147456

__global__ void cast_all_kernel(const float* __restrict__ x, const float* __restrict__ wq,
                                const float* __restrict__ wk, const float* __restrict__ wv,
                                unsigned short* __restrict__ dx, unsigned short* __restrict__ dq,
                                unsigned short* __restrict__ dk, unsigned short* __restrict__ dv) {
  int i = blockIdx.x * blockDim.x + threadIdx.x;
  const float* s;
  unsigned short* d;
  int off;
  if (i < XN4) {
    s = x; d = dx; off = i;
  } else {
    int j = i - XN4;
    int wi = j / WN4;
    off = j - wi * WN4;
    s = (wi == 0) ? wq : ((wi == 1) ? wk : wv);
    d = (wi == 0) ? dq : ((wi == 1) ? dk : dv);
  }
  float4 v = ((const float4*)s)[off];
  ushort4 r; r.x = f2bf(v.x); r.y = f2bf(v.y); r.z = f2bf(v.z); r.w = f2bf(v.w);
  ((ushort4*)d)[off] = r;
}

// ---------------- projection GEMM: C[m][n] = sum_k X[m][k]*W[n][k] ----------------
// z==2 writes V in key-blocked layout: Vt_blk[key>>5][vr 768][key&31]
__global__ __launch_bounds__(256, 2)
void proj_kernel(const unsigned short* __restrict__ X,
                 const unsigned short* __restrict__ Wq,
                 const unsigned short* __restrict__ Wk,
                 const unsigned short* __restrict__ Wv,
                 unsigned short* __restrict__ Qb,
                 unsigned short* __restrict__ Kb,
                 unsigned short* __restrict__ Vtb) {
  __shared__ __align__(16) char lds[65536];
  const int tid = threadIdx.x;
  const int lane = tid & 63, wv = tid >> 6;
  const int l15 = lane & 15, l4 = lane >> 4;
  const int mt = blockIdx.x, nt = blockIdx.y, z = blockIdx.z;
  const unsigned short* W = (z == 0) ? Wq : ((z == 1) ? Wk : Wv);

  f32x4 acc[4][4];
#pragma unroll
  for (int i = 0; i < 4; ++i)
#pragma unroll
    for (int j = 0; j < 4; ++j) acc[i][j] = f32x4{0.f, 0.f, 0.f, 0.f};

  auto stage = [&](int kk) {
    char* At = lds + (kk & 1) * 32768;
    char* Bt = At + 16384;
    const int d0 = kk * 64;
#pragma unroll
    for (int i = 0; i < 4; ++i) {
      int s = i * 256 + tid;
      int row = s >> 3, c = (s & 7) ^ (row & 7);
      gll16(X + (long)(mt * 128 + row) * DIM + d0 + c * 8, At + i * 4096 + (wv << 10));
      gll16(W + (long)(nt * 128 + row) * DIM + d0 + c * 8, Bt + i * 4096 + (wv << 10));
    }
  };

  stage(0);
#pragma unroll 1
  for (int kk = 0; kk < 12; ++kk) {
    __syncthreads();
    if (kk + 1 < 12) stage(kk + 1);
    const char* At = lds + (kk & 1) * 32768;
    const char* Bt = At + 16384;
#pragma unroll
    for (int ks = 0; ks < 2; ++ks) {
      const int c = ks * 4 + l4;
      s16x8 a[4], b[4];
#pragma unroll
      for (int mi = 0; mi < 4; ++mi) {
        int row = (wv & 1) * 64 + mi * 16 + l15;
        a[mi] = *(const s16x8*)(At + row * 128 + ((c ^ (row & 7)) << 4));
      }
#pragma unroll
      for (int ni = 0; ni < 4; ++ni) {
        int row = (wv >> 1) * 64 + ni * 16 + l15;
        b[ni] = *(const s16x8*)(Bt + row * 128 + ((c ^ (row & 7)) << 4));
      }
#pragma unroll
      for (int mi = 0; mi < 4; ++mi)
#pragma unroll
        for (int ni = 0; ni < 4; ++ni)
          acc[mi][ni] = __builtin_amdgcn_mfma_f32_16x16x32_bf16(a[mi], b[ni], acc[mi][ni], 0, 0, 0);
    }
  }

#pragma unroll
  for (int mi = 0; mi < 4; ++mi)
#pragma unroll
    for (int ni = 0; ni < 4; ++ni) {
      int row0 = mt * 128 + (wv & 1) * 64 + mi * 16 + l4 * 4;
      int col = nt * 128 + (wv >> 1) * 64 + ni * 16 + l15;
      if (z == 2) {
        ushort4 r;
        r.x = f2bf(acc[mi][ni][0]); r.y = f2bf(acc[mi][ni][1]);
        r.z = f2bf(acc[mi][ni][2]); r.w = f2bf(acc[mi][ni][3]);
        // blocked: [row0>>5][col][row0&31]; keys row0..row0+3 stay in one 32-block
        *(ushort4*)(Vtb + (long)(row0 >> 5) * (DIM * 32) + col * 32 + (row0 & 31)) = r;
      } else {
        unsigned short* dst = (z == 0) ? Qb : Kb;
#pragma unroll
        for (int g = 0; g < 4; ++g)
          dst[(long)(row0 + g) * DIM + col] = f2bf(acc[mi][ni][g]);
      }
    }
}

// ---------------- flash attention (R4 skeleton, verified 316us; + setprio + pa prefetch) ----
// BM=64 q rows/block, BN=256 keys/iter, 8 waves, all 16x16x32 MFMA.
// QK phase: identical to R4. PV: 8 chunks of 32 keys x full 768 vr; pa fragments
// for chunk v+1 prefetched into ping-pong regs during chunk v (P is read-only in
// the PV phase; next __syncthreads lgkm-drains the reads -> hazard-free).
// setprio(1) wraps each MFMA cluster (T5). No sync/layout change vs R4.
// LDS map: QK B0=[0..40960) B1=[40960..81920); V slotA chunks {0,8K,16K,24K,32K,80K},
//   slotB chunks {40K,48K,56K,64K,72K,88K} (8KB each; tails in [81920..98304));
//   P=[98304..131072); l_part aliases arena[0..1024) post-loop.
#define SCALE_LOG2E 0.05205878f  // (1/sqrt(768)) * log2(e)

__global__ __launch_bounds__(512, 2)
void flash_kernel(const unsigned short* __restrict__ Q,   // [8192][768] bf16
                  const unsigned short* __restrict__ K,   // [8192][768] bf16
                  const unsigned short* __restrict__ V,   // blocked Vt [256][768][32] bf16
                  unsigned short* __restrict__ partp,     // [G][8192][768] bf16 (G-split mode)
                  float* __restrict__ outf,               // [8192][768] fp32 (norm mode)
                  float* __restrict__ lout,               // [G][8192] (G-split mode)
                  int kv_len, int norm_out) {
  __shared__ __align__(16) char lds[131072];
  char* Pl = lds + 98304;
  float* l_part = (float*)lds;  // [4][64], used only after the main loop

  const int tid = threadIdx.x;
  const int lane = tid & 63, wv = tid >> 6;
  const int l15 = lane & 15, l4 = lane >> 4;
  const int qtile = blockIdx.x, split = blockIdx.y;
  const long kv0 = (long)split * kv_len;
  const long qrow0 = (long)qtile * 64;
  const int R = wv & 1;   // S row-half
  const int C = wv >> 1;  // S key-quarter

  f32x4 acc_o[4][6];
  float acc_lp[8];
#pragma unroll
  for (int i = 0; i < 4; ++i)
#pragma unroll
    for (int j = 0; j < 6; ++j) acc_o[i][j] = f32x4{0.f, 0.f, 0.f, 0.f};
#pragma unroll
  for (int i = 0; i < 8; ++i) acc_lp[i] = 0.f;

  const int niter = kv_len >> 8;

  // V chunk base: parity 0 -> {0..32K, 80K}, parity 1 -> {40K..72K, 88K}
  auto vchunk = [&](int par, int j) -> char* {
    int base = par ? ((j < 5) ? 40960 + j * 8192 : 90112)
                   : ((j < 5) ? j * 8192 : 81920);
    return lds + base;
  };

  auto stageQK = [&](int r, long kbase) {
    char* Qc = lds + (r & 1) * 40960;
    char* Kc = Qc + 8192;
    const int d0 = r * 64;
    {
      int s = tid;
      int row = s >> 3, c = (s & 7) ^ (row & 7);
      gll16(Q + (qrow0 + row) * DIM + d0 + c * 8, Qc + (wv << 10));
    }
#pragma unroll
    for (int i = 0; i < 4; ++i) {
      int s = i * 512 + tid;
      int row = s >> 3, c = (s & 7) ^ (row & 7);
      gll16(K + (kbase + row) * DIM + d0 + c * 8, Kc + i * 8192 + (wv << 10));
    }
  };

  // stage V block (kblk0+v): 48KB = 6 chunks of [128 vr][64B]; within a chunk,
  // data (vr,k4) lives at slot rp*8 + p3, rp=vr>>1, p3=(((vr&1)<<2)|k4)^(rp&7).
  // Linear LDS dest -> inverse-swizzle the global source (G21).
  auto stagePV = [&](int v, long kblk0) {
    const int par = v & 1;
    const long blkbase = (kblk0 + v) * (long)(DIM * 32);
    int s = wv * 64 + lane;          // slot within chunk (dest = base + lane*16)
    int rp = s >> 3, p3 = s & 7;
    int orig = p3 ^ (rp & 7);
    int vr_in = rp * 2 + (orig >> 2);
    int k4 = orig & 3;
#pragma unroll
    for (int i = 0; i < 6; ++i)
      gll16(V + blkbase + (long)(i * 128 + vr_in) * 32 + k4 * 8, vchunk(par, i) + (wv << 10));
  };

  stageQK(0, kv0);
#pragma unroll 1
  for (int it = 0; it < niter; ++it) {
    const long kb = kv0 + (long)it * 256;
    const long kblk0 = kb >> 5;

    // ---- QK: S[64x256], per-wave region [32 rows x 64 keys] = 2x4 16x16 tiles ----
    f32x4 acc_s[2][4];
#pragma unroll
    for (int a = 0; a < 2; ++a)
#pragma unroll
      for (int b = 0; b < 4; ++b) acc_s[a][b] = f32x4{0.f, 0.f, 0.f, 0.f};

#pragma unroll 1
    for (int r = 0; r < 12; ++r) {
      __syncthreads();  // drains stage(r); all waves done with prior compute
      if (r + 1 < 12) stageQK(r + 1, kb);
      else stagePV(0, kblk0);  // dest B0+tailA; r=11 reads B1 -> disjoint
      const char* Qc = lds + (r & 1) * 40960;
      const char* Kc = Qc + 8192;
#pragma unroll
      for (int ks = 0; ks < 2; ++ks) {
        const int c = ks * 4 + l4;
        s16x8 af[2], bk[4];
#pragma unroll
        for (int rt = 0; rt < 2; ++rt) {
          int row = R * 32 + rt * 16 + l15;
          af[rt] = *(const s16x8*)(Qc + row * 128 + ((c ^ (row & 7)) << 4));
        }
#pragma unroll
        for (int ct = 0; ct < 4; ++ct) {
          int kr = C * 64 + ct * 16 + l15;
          bk[ct] = *(const s16x8*)(Kc + kr * 128 + ((c ^ (kr & 7)) << 4));
        }
        __builtin_amdgcn_s_setprio(1);
#pragma unroll
        for (int rt = 0; rt < 2; ++rt)
#pragma unroll
          for (int ct = 0; ct < 4; ++ct)
            acc_s[rt][ct] = __builtin_amdgcn_mfma_f32_16x16x32_bf16(af[rt], bk[ct], acc_s[rt][ct], 0, 0, 0);
        __builtin_amdgcn_s_setprio(0);
      }
    }

    // ---- P = exp(S/sqrt(D)) -> bf16 -> LDS (swizzled [64][256]); per-lane l partials ----
#pragma unroll
    for (int rt = 0; rt < 2; ++rt)
#pragma unroll
      for (int ct = 0; ct < 4; ++ct)
#pragma unroll
        for (int g = 0; g < 4; ++g) {
          float p = exp2f(acc_s[rt][ct][g] * SCALE_LOG2E);
          acc_lp[rt * 4 + g] += p;
          int row = R * 32 + rt * 16 + l4 * 4 + g;
          int col = C * 64 + ct * 16 + l15;
          int off = row * 512 + ((((col >> 3) ^ (row & 7))) << 4) + ((col & 7) << 1);
          *(unsigned short*)(Pl + off) = f2bf(p);
        }

    // ---- PV: O[64x768] += P[64x256] @ V; 8 chunks of 32 keys x full 768 d ----
    // pa ping-pong prefetch: chunk v prefetches chunk v+1's P fragments (P is
    // read-only during PV; next barrier's lgkm drain completes them).
    s16x8 paA[4], paB[4];
    auto ldp = [&](s16x8 (&pp)[4], int v) {
      const int ck = v * 4 + l4;
#pragma unroll
      for (int rs = 0; rs < 4; ++rs) {
        int row = rs * 16 + l15;
        int pc = (ck & ~7) | ((ck & 7) ^ (row & 7));
        pp[rs] = *(const s16x8*)(Pl + row * 512 + (pc << 4));
      }
    };
    auto pvchunk = [&](s16x8 (&pa)[4], s16x8 (&pn)[4], int v, bool first) {
      __syncthreads();  // drains stage(v) (+P ds_writes at v=0); prev readers done
      if (v + 1 < 8) stagePV(v + 1, kblk0);
      else if (it + 1 < niter) stageQK(0, kb + 256);  // dest B0; v=7 reads slotB
      if (first) ldp(pa, 0);          // chunk 0: own pa, after P-visibility barrier
      const int par = v & 1;
      const int vr_l = wv * 16 + l15;          // vr & 127 (same for all sub-chunks)
      const int rp = vr_l >> 1;
      const int p3 = (((l15 & 1) << 2) | l4) ^ (rp & 7);
#pragma unroll
      for (int cc = 0; cc < 3; ++cc)
#pragma unroll
        for (int t = 0; t < 2; ++t) {
          const char* vcb = vchunk(par, cc * 2 + t);
          s16x8 vb = *(const s16x8*)(vcb + rp * 128 + (p3 << 4));
          __builtin_amdgcn_s_setprio(1);
#pragma unroll
          for (int rs = 0; rs < 4; ++rs)
            acc_o[rs][cc * 2 + t] =
                __builtin_amdgcn_mfma_f32_16x16x32_bf16(pa[rs], vb, acc_o[rs][cc * 2 + t], 0, 0, 0);
          __builtin_amdgcn_s_setprio(0);
        }
      if (v + 1 < 8) ldp(pn, v + 1);  // prefetch next chunk's pa (completes at next barrier)
    };
    pvchunk(paA, paB, 0, true);
    pvchunk(paB, paA, 1, false);
    pvchunk(paA, paB, 2, false);
    pvchunk(paB, paA, 3, false);
    pvchunk(paA, paB, 4, false);
    pvchunk(paB, paA, 5, false);
    pvchunk(paA, paB, 6, false);
    pvchunk(paB, paA, 7, false);
  }

  // ---- l reduction: butterfly over lane bits 0..3 (16 cols/group), combine quarters ----
#pragma unroll
  for (int i = 0; i < 8; ++i) {
    float v = acc_lp[i];
    v += __shfl_xor(v, 1); v += __shfl_xor(v, 2);
    v += __shfl_xor(v, 4); v += __shfl_xor(v, 8);
    acc_lp[i] = v;
  }
  __syncthreads();  // all arena staging/reads done before l_part alias use
  if (l15 == 0) {
#pragma unroll
    for (int rt = 0; rt < 2; ++rt)
#pragma unroll
      for (int g = 0; g < 4; ++g)
        l_part[C * 64 + R * 32 + rt * 16 + l4 * 4 + g] = acc_lp[rt * 4 + g];
  }
  __syncthreads();

  if (!norm_out) {
    if (tid < 64)
      lout[(long)split * SEQ + qrow0 + tid] =
          l_part[tid] + l_part[64 + tid] + l_part[128 + tid] + l_part[192 + tid];
#pragma unroll
    for (int rt = 0; rt < 4; ++rt) {
      int row = rt * 16 + l4 * 4;
#pragma unroll
      for (int j = 0; j < 6; ++j) {
        int cc = j >> 1, t = j & 1;
        int col = (cc * 16 + wv + 8 * t) * 16 + l15;
#pragma unroll
        for (int g = 0; g < 4; ++g)
          partp[(long)split * SEQ * DIM + (qrow0 + row + g) * DIM + col] = f2bf(acc_o[rt][j][g]);
      }
    }
  } else {
    float linv[4][4];
#pragma unroll
    for (int rt = 0; rt < 4; ++rt)
#pragma unroll
      for (int g = 0; g < 4; ++g) {
        int row = rt * 16 + l4 * 4 + g;
        linv[rt][g] = 1.0f / (l_part[row] + l_part[64 + row] + l_part[128 + row] + l_part[192 + row]);
      }
#pragma unroll
    for (int rt = 0; rt < 4; ++rt) {
      int row = rt * 16 + l4 * 4;
#pragma unroll
      for (int j = 0; j < 6; ++j) {
        int cc = j >> 1, t = j & 1;
        int col = (cc * 16 + wv + 8 * t) * 16 + l15;
#pragma unroll
        for (int g = 0; g < 4; ++g)
          outf[(qrow0 + row + g) * DIM + col] = acc_o[rt][j][g] * linv[rt][g];
      }
    }
  }
}

// ---------------- combine (G splits): out = (sum p_g) / (sum l_g), partials bf16 ----------------
__global__ void combine_kernel(const unsigned short* __restrict__ part,
                               const float* __restrict__ lsum,
                               float* __restrict__ out, int n4, int nsplit) {
  int i = blockIdx.x * blockDim.x + threadIdx.x;
  if (i >= n4) return;
  int row = (i * 4) / DIM;
  float4 o = {0.f, 0.f, 0.f, 0.f};
  float l = 0.f;
#pragma unroll 4
  for (int g = 0; g < nsplit; ++g) {
    ushort4 p = ((const ushort4*)(part + (long)g * SEQ * DIM))[i];
    o.x += bf2f(p.x); o.y += bf2f(p.y); o.z += bf2f(p.z); o.w += bf2f(p.w);
    l += lsum[(long)g * SEQ + row];
  }
  float inv = 1.0f / l;
  o.x *= inv; o.y *= inv; o.z *= inv; o.w *= inv;
  ((float4*)out)[i] = o;
}

// ---------------- host ----------------
extern "C" void kernel_launch(void* const* d_in, const int* in_sizes, int n_in,
                              void* d_out, int out_size, void* d_ws, size_t ws_size,
                              hipStream_t stream) {
  const float* x = (const float*)d_in[0];
  const float* wq = (const float*)d_in[1];
  const float* wk = (const float*)d_in[2];
  const float* wv = (const float*)d_in[3];
  float* out = (float*)d_out;
  char* ws = (char*)d_ws;

  const size_t o_xbf = 0;
  const size_t o_wq = o_xbf + (size_t)SEQ * DIM * 2;
  const size_t o_wk = o_wq + (size_t)DIM * DIM * 2;
  const size_t o_wv = o_wk + (size_t)DIM * DIM * 2;
  const size_t o_q = o_wv + (size_t)DIM * DIM * 2;
  const size_t o_k = o_q + (size_t)SEQ * DIM * 2;
  const size_t o_vt = o_k + (size_t)SEQ * DIM * 2;
  const size_t o_part = o_vt + (size_t)SEQ * DIM * 2;
  const size_t o_l4 = o_part + (size_t)4 * SEQ * DIM * 2;
  const size_t total_g4 = o_l4 + (size_t)4 * SEQ * 4;
  const size_t o_l2 = o_part + (size_t)2 * SEQ * DIM * 2;
  const size_t total_g2 = o_l2 + (size_t)2 * SEQ * 4;

  unsigned short* Xbf = (unsigned short*)(ws + o_xbf);
  unsigned short* Wqb = (unsigned short*)(ws + o_wq);
  unsigned short* Wkb = (unsigned short*)(ws + o_wk);
  unsigned short* Wvb = (unsigned short*)(ws + o_wv);
  unsigned short* Qb = (unsigned short*)(ws + o_q);
  unsigned short* Kb = (unsigned short*)(ws + o_k);
  unsigned short* Vtb = (unsigned short*)(ws + o_vt);
  unsigned short* part = (unsigned short*)(ws + o_part);

  int G;
  size_t o_l;
  if (ws_size >= total_g4) { G = 4; o_l = o_l4; }
  else if (ws_size >= total_g2) { G = 2; o_l = o_l2; }
  else { G = 1; o_l = o_part; }
  float* lbuf = (float*)(ws + o_l);

  cast_all_kernel<<<7872, 256, 0, stream>>>(x, wq, wk, wv, Xbf, Wqb, Wkb, Wvb);
  proj_kernel<<<dim3(64, 6, 3), 256, 0, stream>>>(Xbf, Wqb, Wkb, Wvb, Qb, Kb, Vtb);
  if (G > 1) {
    flash_kernel<<<dim3(128, G), 512, 0, stream>>>(Qb, Kb, Vtb, part, nullptr, lbuf, SEQ / G, 0);
    combine_kernel<<<6144, 256, 0, stream>>>(part, lbuf, out, SEQ * DIM / 4, G);
  } else {
    flash_kernel<<<dim3(128, 1), 512, 0, stream>>>(Qb, Kb, Vtb, nullptr, out, nullptr, SEQ, 1);
  }
}

// Round 9
// 315.923 us; speedup vs baseline: 3.2998x; 1.4725x over previous
//
#include <hip/hip_runtime.h>

#define SEQ 8192
#define DIM 768

typedef __attribute__((ext_vector_type(8))) short s16x8;   // 8 x bf16
typedef __attribute__((ext_vector_type(4))) float f32x4;

// RNE float -> bf16
__device__ __forceinline__ unsigned short f2bf(float f) {
  union { float f; unsigned u; } v; v.f = f;
  unsigned r = v.u + 0x7FFFu + ((v.u >> 16) & 1u);
  return (unsigned short)(r >> 16);
}

__device__ __forceinline__ float bf2f(unsigned short s) {
  union { unsigned u; float f; } v; v.u = ((unsigned)s) << 16;
  return v.f;
}

// async global->LDS 16B copy: lds dest = wave-uniform base + lane*16
__device__ __forceinline__ void gll16(const void* gsrc, void* ldst) {
  __builtin_amdgcn_global_load_lds(
      (__attribute__((address_space(1))) unsigned int*)gsrc,
      (__attribute__((address_space(3))) unsigned int*)ldst, 16, 0, 0);
}

// ---------------- fused cast kernel: x (6144 blocks) + wq/wk/wv (576 each) ----------------
#define XN4 (SEQ * DIM / 4)     // 1572864
#define WN4 (DIM * DIM / 4)     // 147456

__global__ void cast_all_kernel(const float* __restrict__ x, const float* __restrict__ wq,
                                const float* __restrict__ wk, const float* __restrict__ wv,
                                unsigned short* __restrict__ dx, unsigned short* __restrict__ dq,
                                unsigned short* __restrict__ dk, unsigned short* __restrict__ dv) {
  int i = blockIdx.x * blockDim.x + threadIdx.x;
  const float* s;
  unsigned short* d;
  int off;
  if (i < XN4) {
    s = x; d = dx; off = i;
  } else {
    int j = i - XN4;
    int wi = j / WN4;
    off = j - wi * WN4;
    s = (wi == 0) ? wq : ((wi == 1) ? wk : wv);
    d = (wi == 0) ? dq : ((wi == 1) ? dk : dv);
  }
  float4 v = ((const float4*)s)[off];
  ushort4 r; r.x = f2bf(v.x); r.y = f2bf(v.y); r.z = f2bf(v.z); r.w = f2bf(v.w);
  ((ushort4*)d)[off] = r;
}

// ---------------- projection GEMM: C[m][n] = sum_k X[m][k]*W[n][k] ----------------
// z==2 writes V in key-blocked layout: Vt_blk[key>>5][vr 768][key&31]
__global__ __launch_bounds__(256, 2)
void proj_kernel(const unsigned short* __restrict__ X,
                 const unsigned short* __restrict__ Wq,
                 const unsigned short* __restrict__ Wk,
                 const unsigned short* __restrict__ Wv,
                 unsigned short* __restrict__ Qb,
                 unsigned short* __restrict__ Kb,
                 unsigned short* __restrict__ Vtb) {
  __shared__ __align__(16) char lds[65536];
  const int tid = threadIdx.x;
  const int lane = tid & 63, wv = tid >> 6;
  const int l15 = lane & 15, l4 = lane >> 4;
  const int mt = blockIdx.x, nt = blockIdx.y, z = blockIdx.z;
  const unsigned short* W = (z == 0) ? Wq : ((z == 1) ? Wk : Wv);

  f32x4 acc[4][4];
#pragma unroll
  for (int i = 0; i < 4; ++i)
#pragma unroll
    for (int j = 0; j < 4; ++j) acc[i][j] = f32x4{0.f, 0.f, 0.f, 0.f};

  auto stage = [&](int kk) {
    char* At = lds + (kk & 1) * 32768;
    char* Bt = At + 16384;
    const int d0 = kk * 64;
#pragma unroll
    for (int i = 0; i < 4; ++i) {
      int s = i * 256 + tid;
      int row = s >> 3, c = (s & 7) ^ (row & 7);
      gll16(X + (long)(mt * 128 + row) * DIM + d0 + c * 8, At + i * 4096 + (wv << 10));
      gll16(W + (long)(nt * 128 + row) * DIM + d0 + c * 8, Bt + i * 4096 + (wv << 10));
    }
  };

  stage(0);
#pragma unroll 1
  for (int kk = 0; kk < 12; ++kk) {
    __syncthreads();
    if (kk + 1 < 12) stage(kk + 1);
    const char* At = lds + (kk & 1) * 32768;
    const char* Bt = At + 16384;
#pragma unroll
    for (int ks = 0; ks < 2; ++ks) {
      const int c = ks * 4 + l4;
      s16x8 a[4], b[4];
#pragma unroll
      for (int mi = 0; mi < 4; ++mi) {
        int row = (wv & 1) * 64 + mi * 16 + l15;
        a[mi] = *(const s16x8*)(At + row * 128 + ((c ^ (row & 7)) << 4));
      }
#pragma unroll
      for (int ni = 0; ni < 4; ++ni) {
        int row = (wv >> 1) * 64 + ni * 16 + l15;
        b[ni] = *(const s16x8*)(Bt + row * 128 + ((c ^ (row & 7)) << 4));
      }
#pragma unroll
      for (int mi = 0; mi < 4; ++mi)
#pragma unroll
        for (int ni = 0; ni < 4; ++ni)
          acc[mi][ni] = __builtin_amdgcn_mfma_f32_16x16x32_bf16(a[mi], b[ni], acc[mi][ni], 0, 0, 0);
    }
  }

#pragma unroll
  for (int mi = 0; mi < 4; ++mi)
#pragma unroll
    for (int ni = 0; ni < 4; ++ni) {
      int row0 = mt * 128 + (wv & 1) * 64 + mi * 16 + l4 * 4;
      int col = nt * 128 + (wv >> 1) * 64 + ni * 16 + l15;
      if (z == 2) {
        ushort4 r;
        r.x = f2bf(acc[mi][ni][0]); r.y = f2bf(acc[mi][ni][1]);
        r.z = f2bf(acc[mi][ni][2]); r.w = f2bf(acc[mi][ni][3]);
        // blocked: [row0>>5][col][row0&31]; keys row0..row0+3 stay in one 32-block
        *(ushort4*)(Vtb + (long)(row0 >> 5) * (DIM * 32) + col * 32 + (row0 & 31)) = r;
      } else {
        unsigned short* dst = (z == 0) ? Qb : Kb;
#pragma unroll
        for (int g = 0; g < 4; ++g)
          dst[(long)(row0 + g) * DIM + col] = f2bf(acc[mi][ni][g]);
      }
    }
}

// ---------------- flash attention (R4 skeleton, verified 316us; + setprio ONLY) ----
// BM=64 q rows/block, BN=256 keys/iter, 8 waves, all 16x16x32 MFMA.
// Identical to the verified R4 kernel except s_setprio(1/0) around MFMA clusters.
// LDS map: QK B0=[0..40960) B1=[40960..81920); V slotA chunks {0,8K,16K,24K,32K,80K},
//   slotB chunks {40K,48K,56K,64K,72K,88K} (8KB each; tails in [81920..98304));
//   P=[98304..131072); l_part aliases arena[0..1024) post-loop.
// Cross-phase prefetch: stagePV(0) at QK r=11 (reads B1; dest in B0+tailA);
//   next-iter stageQK(0) at PV v=7 (reads slotB; dest B0). Depth stays 1.
#define SCALE_LOG2E 0.05205878f  // (1/sqrt(768)) * log2(e)

__global__ __launch_bounds__(512, 2)
void flash_kernel(const unsigned short* __restrict__ Q,   // [8192][768] bf16
                  const unsigned short* __restrict__ K,   // [8192][768] bf16
                  const unsigned short* __restrict__ V,   // blocked Vt [256][768][32] bf16
                  unsigned short* __restrict__ partp,     // [G][8192][768] bf16 (G-split mode)
                  float* __restrict__ outf,               // [8192][768] fp32 (norm mode)
                  float* __restrict__ lout,               // [G][8192] (G-split mode)
                  int kv_len, int norm_out) {
  __shared__ __align__(16) char lds[131072];
  char* Pl = lds + 98304;
  float* l_part = (float*)lds;  // [4][64], used only after the main loop

  const int tid = threadIdx.x;
  const int lane = tid & 63, wv = tid >> 6;
  const int l15 = lane & 15, l4 = lane >> 4;
  const int qtile = blockIdx.x, split = blockIdx.y;
  const long kv0 = (long)split * kv_len;
  const long qrow0 = (long)qtile * 64;
  const int R = wv & 1;   // S row-half
  const int C = wv >> 1;  // S key-quarter

  f32x4 acc_o[4][6];
  float acc_lp[8];
#pragma unroll
  for (int i = 0; i < 4; ++i)
#pragma unroll
    for (int j = 0; j < 6; ++j) acc_o[i][j] = f32x4{0.f, 0.f, 0.f, 0.f};
#pragma unroll
  for (int i = 0; i < 8; ++i) acc_lp[i] = 0.f;

  const int niter = kv_len >> 8;

  // V chunk base: parity 0 -> {0..32K, 80K}, parity 1 -> {40K..72K, 88K}
  auto vchunk = [&](int par, int j) -> char* {
    int base = par ? ((j < 5) ? 40960 + j * 8192 : 90112)
                   : ((j < 5) ? j * 8192 : 81920);
    return lds + base;
  };

  auto stageQK = [&](int r, long kbase) {
    char* Qc = lds + (r & 1) * 40960;
    char* Kc = Qc + 8192;
    const int d0 = r * 64;
    {
      int s = tid;
      int row = s >> 3, c = (s & 7) ^ (row & 7);
      gll16(Q + (qrow0 + row) * DIM + d0 + c * 8, Qc + (wv << 10));
    }
#pragma unroll
    for (int i = 0; i < 4; ++i) {
      int s = i * 512 + tid;
      int row = s >> 3, c = (s & 7) ^ (row & 7);
      gll16(K + (kbase + row) * DIM + d0 + c * 8, Kc + i * 8192 + (wv << 10));
    }
  };

  // stage V block (kblk0+v): 48KB = 6 chunks of [128 vr][64B]; within a chunk,
  // data (vr,k4) lives at slot rp*8 + p3, rp=vr>>1, p3=(((vr&1)<<2)|k4)^(rp&7).
  // Linear LDS dest -> inverse-swizzle the global source (G21).
  auto stagePV = [&](int v, long kblk0) {
    const int par = v & 1;
    const long blkbase = (kblk0 + v) * (long)(DIM * 32);
    int s = wv * 64 + lane;          // slot within chunk (dest = base + lane*16)
    int rp = s >> 3, p3 = s & 7;
    int orig = p3 ^ (rp & 7);
    int vr_in = rp * 2 + (orig >> 2);
    int k4 = orig & 3;
#pragma unroll
    for (int i = 0; i < 6; ++i)
      gll16(V + blkbase + (long)(i * 128 + vr_in) * 32 + k4 * 8, vchunk(par, i) + (wv << 10));
  };

  stageQK(0, kv0);
#pragma unroll 1
  for (int it = 0; it < niter; ++it) {
    const long kb = kv0 + (long)it * 256;
    const long kblk0 = kb >> 5;

    // ---- QK: S[64x256], per-wave region [32 rows x 64 keys] = 2x4 16x16 tiles ----
    f32x4 acc_s[2][4];
#pragma unroll
    for (int a = 0; a < 2; ++a)
#pragma unroll
      for (int b = 0; b < 4; ++b) acc_s[a][b] = f32x4{0.f, 0.f, 0.f, 0.f};

#pragma unroll 1
    for (int r = 0; r < 12; ++r) {
      __syncthreads();  // drains stage(r); all waves done with prior compute
      if (r + 1 < 12) stageQK(r + 1, kb);
      else stagePV(0, kblk0);  // dest B0+tailA; r=11 reads B1 -> disjoint
      const char* Qc = lds + (r & 1) * 40960;
      const char* Kc = Qc + 8192;
#pragma unroll
      for (int ks = 0; ks < 2; ++ks) {
        const int c = ks * 4 + l4;
        s16x8 af[2], bk[4];
#pragma unroll
        for (int rt = 0; rt < 2; ++rt) {
          int row = R * 32 + rt * 16 + l15;
          af[rt] = *(const s16x8*)(Qc + row * 128 + ((c ^ (row & 7)) << 4));
        }
#pragma unroll
        for (int ct = 0; ct < 4; ++ct) {
          int kr = C * 64 + ct * 16 + l15;
          bk[ct] = *(const s16x8*)(Kc + kr * 128 + ((c ^ (kr & 7)) << 4));
        }
        __builtin_amdgcn_s_setprio(1);
#pragma unroll
        for (int rt = 0; rt < 2; ++rt)
#pragma unroll
          for (int ct = 0; ct < 4; ++ct)
            acc_s[rt][ct] = __builtin_amdgcn_mfma_f32_16x16x32_bf16(af[rt], bk[ct], acc_s[rt][ct], 0, 0, 0);
        __builtin_amdgcn_s_setprio(0);
      }
    }

    // ---- P = exp(S/sqrt(D)) -> bf16 -> LDS (swizzled [64][256]); per-lane l partials ----
#pragma unroll
    for (int rt = 0; rt < 2; ++rt)
#pragma unroll
      for (int ct = 0; ct < 4; ++ct)
#pragma unroll
        for (int g = 0; g < 4; ++g) {
          float p = exp2f(acc_s[rt][ct][g] * SCALE_LOG2E);
          acc_lp[rt * 4 + g] += p;
          int row = R * 32 + rt * 16 + l4 * 4 + g;
          int col = C * 64 + ct * 16 + l15;
          int off = row * 512 + ((((col >> 3) ^ (row & 7))) << 4) + ((col & 7) << 1);
          *(unsigned short*)(Pl + off) = f2bf(p);
        }

    // ---- PV: O[64x768] += P[64x256] @ V; 8 chunks of 32 keys x full 768 d ----
#pragma unroll 1
    for (int v = 0; v < 8; ++v) {
      __syncthreads();  // drains stage(v) (+P ds_writes at v=0); prev readers done
      if (v + 1 < 8) stagePV(v + 1, kblk0);
      else if (it + 1 < niter) stageQK(0, kb + 256);  // dest B0; v=7 reads slotB
      const int par = v & 1;
      s16x8 pa[4];
      const int ck = v * 4 + l4;
#pragma unroll
      for (int rs = 0; rs < 4; ++rs) {
        int row = rs * 16 + l15;
        int pc = (ck & ~7) | ((ck & 7) ^ (row & 7));
        pa[rs] = *(const s16x8*)(Pl + row * 512 + (pc << 4));
      }
      const int vr_l = wv * 16 + l15;          // vr & 127 (same for t=0,1)
      const int rp = vr_l >> 1;
      const int p3 = (((l15 & 1) << 2) | l4) ^ (rp & 7);
#pragma unroll
      for (int cc = 0; cc < 3; ++cc)
#pragma unroll
        for (int t = 0; t < 2; ++t) {
          const char* vcb = vchunk(par, cc * 2 + t);
          s16x8 vb = *(const s16x8*)(vcb + rp * 128 + (p3 << 4));
          __builtin_amdgcn_s_setprio(1);
#pragma unroll
          for (int rs = 0; rs < 4; ++rs)
            acc_o[rs][cc * 2 + t] =
                __builtin_amdgcn_mfma_f32_16x16x32_bf16(pa[rs], vb, acc_o[rs][cc * 2 + t], 0, 0, 0);
          __builtin_amdgcn_s_setprio(0);
        }
    }
  }

  // ---- l reduction: butterfly over lane bits 0..3 (16 cols/group), combine quarters ----
#pragma unroll
  for (int i = 0; i < 8; ++i) {
    float v = acc_lp[i];
    v += __shfl_xor(v, 1); v += __shfl_xor(v, 2);
    v += __shfl_xor(v, 4); v += __shfl_xor(v, 8);
    acc_lp[i] = v;
  }
  __syncthreads();  // all arena staging/reads done before l_part alias use
  if (l15 == 0) {
#pragma unroll
    for (int rt = 0; rt < 2; ++rt)
#pragma unroll
      for (int g = 0; g < 4; ++g)
        l_part[C * 64 + R * 32 + rt * 16 + l4 * 4 + g] = acc_lp[rt * 4 + g];
  }
  __syncthreads();

  if (!norm_out) {
    if (tid < 64)
      lout[(long)split * SEQ + qrow0 + tid] =
          l_part[tid] + l_part[64 + tid] + l_part[128 + tid] + l_part[192 + tid];
#pragma unroll
    for (int rt = 0; rt < 4; ++rt) {
      int row = rt * 16 + l4 * 4;
#pragma unroll
      for (int j = 0; j < 6; ++j) {
        int cc = j >> 1, t = j & 1;
        int col = (cc * 16 + wv + 8 * t) * 16 + l15;
#pragma unroll
        for (int g = 0; g < 4; ++g)
          partp[(long)split * SEQ * DIM + (qrow0 + row + g) * DIM + col] = f2bf(acc_o[rt][j][g]);
      }
    }
  } else {
    float linv[4][4];
#pragma unroll
    for (int rt = 0; rt < 4; ++rt)
#pragma unroll
      for (int g = 0; g < 4; ++g) {
        int row = rt * 16 + l4 * 4 + g;
        linv[rt][g] = 1.0f / (l_part[row] + l_part[64 + row] + l_part[128 + row] + l_part[192 + row]);
      }
#pragma unroll
    for (int rt = 0; rt < 4; ++rt) {
      int row = rt * 16 + l4 * 4;
#pragma unroll
      for (int j = 0; j < 6; ++j) {
        int cc = j >> 1, t = j & 1;
        int col = (cc * 16 + wv + 8 * t) * 16 + l15;
#pragma unroll
        for (int g = 0; g < 4; ++g)
          outf[(qrow0 + row + g) * DIM + col] = acc_o[rt][j][g] * linv[rt][g];
      }
    }
  }
}

// ---------------- combine (G=2): out = (p0+p1)/(l0+l1), partials bf16 ----------------
__global__ void combine_kernel(const unsigned short* __restrict__ part,
                               const float* __restrict__ lsum,
                               float* __restrict__ out, int n4) {
  int i = blockIdx.x * blockDim.x + threadIdx.x;
  if (i >= n4) return;
  int row = (i * 4) / DIM;
  ushort4 p0 = ((const ushort4*)part)[i];
  ushort4 p1 = ((const ushort4*)(part + (long)SEQ * DIM))[i];
  float inv = 1.0f / (lsum[row] + lsum[SEQ + row]);
  float4 o;
  o.x = (bf2f(p0.x) + bf2f(p1.x)) * inv;
  o.y = (bf2f(p0.y) + bf2f(p1.y)) * inv;
  o.z = (bf2f(p0.z) + bf2f(p1.z)) * inv;
  o.w = (bf2f(p0.w) + bf2f(p1.w)) * inv;
  ((float4*)out)[i] = o;
}

// ---------------- host (G=2 max — the verified fast config) ----------------
extern "C" void kernel_launch(void* const* d_in, const int* in_sizes, int n_in,
                              void* d_out, int out_size, void* d_ws, size_t ws_size,
                              hipStream_t stream) {
  const float* x = (const float*)d_in[0];
  const float* wq = (const float*)d_in[1];
  const float* wk = (const float*)d_in[2];
  const float* wv = (const float*)d_in[3];
  float* out = (float*)d_out;
  char* ws = (char*)d_ws;

  const size_t o_xbf = 0;
  const size_t o_wq = o_xbf + (size_t)SEQ * DIM * 2;
  const size_t o_wk = o_wq + (size_t)DIM * DIM * 2;
  const size_t o_wv = o_wk + (size_t)DIM * DIM * 2;
  const size_t o_q = o_wv + (size_t)DIM * DIM * 2;
  const size_t o_k = o_q + (size_t)SEQ * DIM * 2;
  const size_t o_vt = o_k + (size_t)SEQ * DIM * 2;
  const size_t o_part = o_vt + (size_t)SEQ * DIM * 2;
  const size_t o_l = o_part + (size_t)2 * SEQ * DIM * 2;   // bf16 partials
  const size_t total_g2 = o_l + (size_t)2 * SEQ * 4;

  unsigned short* Xbf = (unsigned short*)(ws + o_xbf);
  unsigned short* Wqb = (unsigned short*)(ws + o_wq);
  unsigned short* Wkb = (unsigned short*)(ws + o_wk);
  unsigned short* Wvb = (unsigned short*)(ws + o_wv);
  unsigned short* Qb = (unsigned short*)(ws + o_q);
  unsigned short* Kb = (unsigned short*)(ws + o_k);
  unsigned short* Vtb = (unsigned short*)(ws + o_vt);
  unsigned short* part = (unsigned short*)(ws + o_part);
  float* lbuf = (float*)(ws + o_l);

  const int G = (ws_size >= total_g2) ? 2 : 1;

  cast_all_kernel<<<7872, 256, 0, stream>>>(x, wq, wk, wv, Xbf, Wqb, Wkb, Wvb);
  proj_kernel<<<dim3(64, 6, 3), 256, 0, stream>>>(Xbf, Wqb, Wkb, Wvb, Qb, Kb, Vtb);
  if (G == 2) {
    flash_kernel<<<dim3(128, 2), 512, 0, stream>>>(Qb, Kb, Vtb, part, nullptr, lbuf, SEQ / 2, 0);
    combine_kernel<<<6144, 256, 0, stream>>>(part, lbuf, out, SEQ * DIM / 4);
  } else {
    flash_kernel<<<dim3(128, 1), 512, 0, stream>>>(Qb, Kb, Vtb, nullptr, out, nullptr, SEQ, 1);
  }
}

// Round 10
// 301.147 us; speedup vs baseline: 3.4617x; 1.0491x over previous
//
#include <hip/hip_runtime.h>

#define SEQ 8192
#define DIM 768

typedef __attribute__((ext_vector_type(8))) short s16x8;   // 8 x bf16
typedef __attribute__((ext_vector_type(4))) float f32x4;

// RNE float -> bf16
__device__ __forceinline__ unsigned short f2bf(float f) {
  union { float f; unsigned u; } v; v.f = f;
  unsigned r = v.u + 0x7FFFu + ((v.u >> 16) & 1u);
  return (unsigned short)(r >> 16);
}

__device__ __forceinline__ float bf2f(unsigned short s) {
  union { unsigned u; float f; } v; v.u = ((unsigned)s) << 16;
  return v.f;
}

// async global->LDS 16B copy: lds dest = wave-uniform base + lane*16
__device__ __forceinline__ void gll16(const void* gsrc, void* ldst) {
  __builtin_amdgcn_global_load_lds(
      (__attribute__((address_space(1))) unsigned int*)gsrc,
      (__attribute__((address_space(3))) unsigned int*)ldst, 16, 0, 0);
}

// ---------------- fused cast kernel: x (6144 blocks) + wq/wk/wv (576 each) ----------------
#define XN4 (SEQ * DIM / 4)     // 1572864
#define WN4 (DIM * DIM / 4)     // 147456

__global__ void cast_all_kernel(const float* __restrict__ x, const float* __restrict__ wq,
                                const float* __restrict__ wk, const float* __restrict__ wv,
                                unsigned short* __restrict__ dx, unsigned short* __restrict__ dq,
                                unsigned short* __restrict__ dk, unsigned short* __restrict__ dv) {
  int i = blockIdx.x * blockDim.x + threadIdx.x;
  const float* s;
  unsigned short* d;
  int off;
  if (i < XN4) {
    s = x; d = dx; off = i;
  } else {
    int j = i - XN4;
    int wi = j / WN4;
    off = j - wi * WN4;
    s = (wi == 0) ? wq : ((wi == 1) ? wk : wv);
    d = (wi == 0) ? dq : ((wi == 1) ? dk : dv);
  }
  float4 v = ((const float4*)s)[off];
  ushort4 r; r.x = f2bf(v.x); r.y = f2bf(v.y); r.z = f2bf(v.z); r.w = f2bf(v.w);
  ((ushort4*)d)[off] = r;
}

// ---------------- projection GEMM: C[m][n] = sum_k X[m][k]*W[n][k] ----------------
// z==2 writes V in key-blocked layout: Vt_blk[key>>5][vr 768][key&31]
__global__ __launch_bounds__(256, 2)
void proj_kernel(const unsigned short* __restrict__ X,
                 const unsigned short* __restrict__ Wq,
                 const unsigned short* __restrict__ Wk,
                 const unsigned short* __restrict__ Wv,
                 unsigned short* __restrict__ Qb,
                 unsigned short* __restrict__ Kb,
                 unsigned short* __restrict__ Vtb) {
  __shared__ __align__(16) char lds[65536];
  const int tid = threadIdx.x;
  const int lane = tid & 63, wv = tid >> 6;
  const int l15 = lane & 15, l4 = lane >> 4;
  const int mt = blockIdx.x, nt = blockIdx.y, z = blockIdx.z;
  const unsigned short* W = (z == 0) ? Wq : ((z == 1) ? Wk : Wv);

  f32x4 acc[4][4];
#pragma unroll
  for (int i = 0; i < 4; ++i)
#pragma unroll
    for (int j = 0; j < 4; ++j) acc[i][j] = f32x4{0.f, 0.f, 0.f, 0.f};

  auto stage = [&](int kk) {
    char* At = lds + (kk & 1) * 32768;
    char* Bt = At + 16384;
    const int d0 = kk * 64;
#pragma unroll
    for (int i = 0; i < 4; ++i) {
      int s = i * 256 + tid;
      int row = s >> 3, c = (s & 7) ^ (row & 7);
      gll16(X + (long)(mt * 128 + row) * DIM + d0 + c * 8, At + i * 4096 + (wv << 10));
      gll16(W + (long)(nt * 128 + row) * DIM + d0 + c * 8, Bt + i * 4096 + (wv << 10));
    }
  };

  stage(0);
#pragma unroll 1
  for (int kk = 0; kk < 12; ++kk) {
    __syncthreads();
    if (kk + 1 < 12) stage(kk + 1);
    const char* At = lds + (kk & 1) * 32768;
    const char* Bt = At + 16384;
#pragma unroll
    for (int ks = 0; ks < 2; ++ks) {
      const int c = ks * 4 + l4;
      s16x8 a[4], b[4];
#pragma unroll
      for (int mi = 0; mi < 4; ++mi) {
        int row = (wv & 1) * 64 + mi * 16 + l15;
        a[mi] = *(const s16x8*)(At + row * 128 + ((c ^ (row & 7)) << 4));
      }
#pragma unroll
      for (int ni = 0; ni < 4; ++ni) {
        int row = (wv >> 1) * 64 + ni * 16 + l15;
        b[ni] = *(const s16x8*)(Bt + row * 128 + ((c ^ (row & 7)) << 4));
      }
#pragma unroll
      for (int mi = 0; mi < 4; ++mi)
#pragma unroll
        for (int ni = 0; ni < 4; ++ni)
          acc[mi][ni] = __builtin_amdgcn_mfma_f32_16x16x32_bf16(a[mi], b[ni], acc[mi][ni], 0, 0, 0);
    }
  }

#pragma unroll
  for (int mi = 0; mi < 4; ++mi)
#pragma unroll
    for (int ni = 0; ni < 4; ++ni) {
      int row0 = mt * 128 + (wv & 1) * 64 + mi * 16 + l4 * 4;
      int col = nt * 128 + (wv >> 1) * 64 + ni * 16 + l15;
      if (z == 2) {
        ushort4 r;
        r.x = f2bf(acc[mi][ni][0]); r.y = f2bf(acc[mi][ni][1]);
        r.z = f2bf(acc[mi][ni][2]); r.w = f2bf(acc[mi][ni][3]);
        // blocked: [row0>>5][col][row0&31]; keys row0..row0+3 stay in one 32-block
        *(ushort4*)(Vtb + (long)(row0 >> 5) * (DIM * 32) + col * 32 + (row0 & 31)) = r;
      } else {
        unsigned short* dst = (z == 0) ? Qb : Kb;
#pragma unroll
        for (int g = 0; g < 4; ++g)
          dst[(long)(row0 + g) * DIM + col] = f2bf(acc[mi][ni][g]);
      }
    }
}

// ---------------- flash attention: QK = R4/R9 verbatim; PV = V direct global->reg ----
// BM=64 q rows/block, BN=256 keys/iter, 8 waves, all 16x16x32 MFMA.
// V is NOT staged in LDS: blocked-Vt fragment reads are already coalesced
// (16 lanes x 64B stride, l4 fills each 64B line -> 16 full lines/wave-load).
// vb ping-pong: chunk v's MFMAs run while chunk v+1's 6 loads are in flight.
// LDS (114688): QK B0=[0,40960) B1=[40960,81920); P=[81920,114688);
//   l_part aliases lds[0,1024) post-loop. Barriers: 12 QK + 1 P-visibility = 13/iter.
// Rotation: QK r reads buf r&1, stages buf (r+1)&1; r=11 (reads B1) stages
//   next-iter QK(0) -> B0 (B0 last read r=10, all waves past r=11 barrier).
// P hazard: P read in PV (barrier-free); next P write is after 12 next-iter QK
//   barriers -> every wave has finished PV before any wave rewrites P.
#define SCALE_LOG2E 0.05205878f  // (1/sqrt(768)) * log2(e)

#define LOADVB(arr, vv)                                                            \
  do {                                                                             \
    const unsigned short* Vb_ = V + (long)(kblk0 + (vv)) * (DIM * 32);             \
    _Pragma("unroll")                                                              \
    for (int j_ = 0; j_ < 6; ++j_)                                                 \
      arr[j_] = *(const s16x8*)(Vb_ + (j_ * 128 + wv * 16 + l15) * 32 + l4 * 8);   \
  } while (0)

#define PVCHUNK(vv, CUR, NXT)                                                      \
  do {                                                                             \
    if ((vv) + 1 < 8) LOADVB(NXT, (vv) + 1);                                       \
    s16x8 pa_[4];                                                                  \
    const int ck_ = (vv) * 4 + l4;                                                 \
    _Pragma("unroll")                                                              \
    for (int rs_ = 0; rs_ < 4; ++rs_) {                                            \
      int row_ = rs_ * 16 + l15;                                                   \
      int pc_ = (ck_ & ~7) | ((ck_ & 7) ^ (row_ & 7));                             \
      pa_[rs_] = *(const s16x8*)(Pl + row_ * 512 + (pc_ << 4));                    \
    }                                                                              \
    __builtin_amdgcn_s_setprio(1);                                                 \
    _Pragma("unroll")                                                              \
    for (int j_ = 0; j_ < 6; ++j_)                                                 \
      _Pragma("unroll")                                                            \
      for (int rs_ = 0; rs_ < 4; ++rs_)                                            \
        acc_o[rs_][j_] =                                                           \
            __builtin_amdgcn_mfma_f32_16x16x32_bf16(pa_[rs_], CUR[j_], acc_o[rs_][j_], 0, 0, 0); \
    __builtin_amdgcn_s_setprio(0);                                                 \
  } while (0)

__global__ __launch_bounds__(512, 2)
void flash_kernel(const unsigned short* __restrict__ Q,   // [8192][768] bf16
                  const unsigned short* __restrict__ K,   // [8192][768] bf16
                  const unsigned short* __restrict__ V,   // blocked Vt [256][768][32] bf16
                  unsigned short* __restrict__ partp,     // [G][8192][768] bf16 (G-split mode)
                  float* __restrict__ outf,               // [8192][768] fp32 (norm mode)
                  float* __restrict__ lout,               // [G][8192] (G-split mode)
                  int kv_len, int norm_out) {
  __shared__ __align__(16) char lds[114688];
  char* Pl = lds + 81920;
  float* l_part = (float*)lds;  // [4][64], used only after the main loop

  const int tid = threadIdx.x;
  const int lane = tid & 63, wv = tid >> 6;
  const int l15 = lane & 15, l4 = lane >> 4;
  const int qtile = blockIdx.x, split = blockIdx.y;
  const long kv0 = (long)split * kv_len;
  const long qrow0 = (long)qtile * 64;
  const int R = wv & 1;   // S row-half
  const int C = wv >> 1;  // S key-quarter

  f32x4 acc_o[4][6];
  float acc_lp[8];
#pragma unroll
  for (int i = 0; i < 4; ++i)
#pragma unroll
    for (int j = 0; j < 6; ++j) acc_o[i][j] = f32x4{0.f, 0.f, 0.f, 0.f};
#pragma unroll
  for (int i = 0; i < 8; ++i) acc_lp[i] = 0.f;

  const int niter = kv_len >> 8;

  auto stageQK = [&](int r, long kbase) {
    char* Qc = lds + (r & 1) * 40960;
    char* Kc = Qc + 8192;
    const int d0 = r * 64;
    {
      int s = tid;
      int row = s >> 3, c = (s & 7) ^ (row & 7);
      gll16(Q + (qrow0 + row) * DIM + d0 + c * 8, Qc + (wv << 10));
    }
#pragma unroll
    for (int i = 0; i < 4; ++i) {
      int s = i * 512 + tid;
      int row = s >> 3, c = (s & 7) ^ (row & 7);
      gll16(K + (kbase + row) * DIM + d0 + c * 8, Kc + i * 8192 + (wv << 10));
    }
  };

  stageQK(0, kv0);
#pragma unroll 1
  for (int it = 0; it < niter; ++it) {
    const long kb = kv0 + (long)it * 256;
    const long kblk0 = kb >> 5;

    // ---- QK: S[64x256], per-wave region [32 rows x 64 keys] = 2x4 16x16 tiles ----
    f32x4 acc_s[2][4];
#pragma unroll
    for (int a = 0; a < 2; ++a)
#pragma unroll
      for (int b = 0; b < 4; ++b) acc_s[a][b] = f32x4{0.f, 0.f, 0.f, 0.f};

#pragma unroll 1
    for (int r = 0; r < 12; ++r) {
      __syncthreads();  // drains stage(r); all waves done with prior compute
      if (r + 1 < 12) stageQK(r + 1, kb);
      else if (it + 1 < niter) stageQK(0, kb + 256);  // dest B0; r=11 reads B1
      const char* Qc = lds + (r & 1) * 40960;
      const char* Kc = Qc + 8192;
#pragma unroll
      for (int ks = 0; ks < 2; ++ks) {
        const int c = ks * 4 + l4;
        s16x8 af[2], bk[4];
#pragma unroll
        for (int rt = 0; rt < 2; ++rt) {
          int row = R * 32 + rt * 16 + l15;
          af[rt] = *(const s16x8*)(Qc + row * 128 + ((c ^ (row & 7)) << 4));
        }
#pragma unroll
        for (int ct = 0; ct < 4; ++ct) {
          int kr = C * 64 + ct * 16 + l15;
          bk[ct] = *(const s16x8*)(Kc + kr * 128 + ((c ^ (kr & 7)) << 4));
        }
        __builtin_amdgcn_s_setprio(1);
#pragma unroll
        for (int rt = 0; rt < 2; ++rt)
#pragma unroll
          for (int ct = 0; ct < 4; ++ct)
            acc_s[rt][ct] = __builtin_amdgcn_mfma_f32_16x16x32_bf16(af[rt], bk[ct], acc_s[rt][ct], 0, 0, 0);
        __builtin_amdgcn_s_setprio(0);
      }
    }

    // ---- prefetch PV chunk 0's V fragments (latency hidden under exp phase) ----
    s16x8 vbA[6], vbB[6];
    LOADVB(vbA, 0);

    // ---- P = exp(S/sqrt(D)) -> bf16 -> LDS (swizzled [64][256]); per-lane l partials ----
#pragma unroll
    for (int rt = 0; rt < 2; ++rt)
#pragma unroll
      for (int ct = 0; ct < 4; ++ct)
#pragma unroll
        for (int g = 0; g < 4; ++g) {
          float p = exp2f(acc_s[rt][ct][g] * SCALE_LOG2E);
          acc_lp[rt * 4 + g] += p;
          int row = R * 32 + rt * 16 + l4 * 4 + g;
          int col = C * 64 + ct * 16 + l15;
          int off = row * 512 + ((((col >> 3) ^ (row & 7))) << 4) + ((col & 7) << 1);
          *(unsigned short*)(Pl + off) = f2bf(p);
        }
    __syncthreads();  // P visible to all waves (also drains vbA / QK0' loads)

    // ---- PV: O[64x768] += P[64x256] @ V; 8 chunks; vb ping-pong from global ----
    PVCHUNK(0, vbA, vbB);
    PVCHUNK(1, vbB, vbA);
    PVCHUNK(2, vbA, vbB);
    PVCHUNK(3, vbB, vbA);
    PVCHUNK(4, vbA, vbB);
    PVCHUNK(5, vbB, vbA);
    PVCHUNK(6, vbA, vbB);
    PVCHUNK(7, vbB, vbA);
  }

  // ---- l reduction: butterfly over lane bits 0..3 (16 cols/group), combine quarters ----
#pragma unroll
  for (int i = 0; i < 8; ++i) {
    float v = acc_lp[i];
    v += __shfl_xor(v, 1); v += __shfl_xor(v, 2);
    v += __shfl_xor(v, 4); v += __shfl_xor(v, 8);
    acc_lp[i] = v;
  }
  __syncthreads();  // all staging/reads done before l_part alias use
  if (l15 == 0) {
#pragma unroll
    for (int rt = 0; rt < 2; ++rt)
#pragma unroll
      for (int g = 0; g < 4; ++g)
        l_part[C * 64 + R * 32 + rt * 16 + l4 * 4 + g] = acc_lp[rt * 4 + g];
  }
  __syncthreads();

  if (!norm_out) {
    if (tid < 64)
      lout[(long)split * SEQ + qrow0 + tid] =
          l_part[tid] + l_part[64 + tid] + l_part[128 + tid] + l_part[192 + tid];
#pragma unroll
    for (int rt = 0; rt < 4; ++rt) {
      int row = rt * 16 + l4 * 4;
#pragma unroll
      for (int j = 0; j < 6; ++j) {
        int cc = j >> 1, t = j & 1;
        int col = (cc * 16 + wv + 8 * t) * 16 + l15;
#pragma unroll
        for (int g = 0; g < 4; ++g)
          partp[(long)split * SEQ * DIM + (qrow0 + row + g) * DIM + col] = f2bf(acc_o[rt][j][g]);
      }
    }
  } else {
    float linv[4][4];
#pragma unroll
    for (int rt = 0; rt < 4; ++rt)
#pragma unroll
      for (int g = 0; g < 4; ++g) {
        int row = rt * 16 + l4 * 4 + g;
        linv[rt][g] = 1.0f / (l_part[row] + l_part[64 + row] + l_part[128 + row] + l_part[192 + row]);
      }
#pragma unroll
    for (int rt = 0; rt < 4; ++rt) {
      int row = rt * 16 + l4 * 4;
#pragma unroll
      for (int j = 0; j < 6; ++j) {
        int cc = j >> 1, t = j & 1;
        int col = (cc * 16 + wv + 8 * t) * 16 + l15;
#pragma unroll
        for (int g = 0; g < 4; ++g)
          outf[(qrow0 + row + g) * DIM + col] = acc_o[rt][j][g] * linv[rt][g];
      }
    }
  }
}

// ---------------- combine (G=2): out = (p0+p1)/(l0+l1), partials bf16 ----------------
__global__ void combine_kernel(const unsigned short* __restrict__ part,
                               const float* __restrict__ lsum,
                               float* __restrict__ out, int n4) {
  int i = blockIdx.x * blockDim.x + threadIdx.x;
  if (i >= n4) return;
  int row = (i * 4) / DIM;
  ushort4 p0 = ((const ushort4*)part)[i];
  ushort4 p1 = ((const ushort4*)(part + (long)SEQ * DIM))[i];
  float inv = 1.0f / (lsum[row] + lsum[SEQ + row]);
  float4 o;
  o.x = (bf2f(p0.x) + bf2f(p1.x)) * inv;
  o.y = (bf2f(p0.y) + bf2f(p1.y)) * inv;
  o.z = (bf2f(p0.z) + bf2f(p1.z)) * inv;
  o.w = (bf2f(p0.w) + bf2f(p1.w)) * inv;
  ((float4*)out)[i] = o;
}

// ---------------- host (G=2 max — the verified fast config) ----------------
extern "C" void kernel_launch(void* const* d_in, const int* in_sizes, int n_in,
                              void* d_out, int out_size, void* d_ws, size_t ws_size,
                              hipStream_t stream) {
  const float* x = (const float*)d_in[0];
  const float* wq = (const float*)d_in[1];
  const float* wk = (const float*)d_in[2];
  const float* wv = (const float*)d_in[3];
  float* out = (float*)d_out;
  char* ws = (char*)d_ws;

  const size_t o_xbf = 0;
  const size_t o_wq = o_xbf + (size_t)SEQ * DIM * 2;
  const size_t o_wk = o_wq + (size_t)DIM * DIM * 2;
  const size_t o_wv = o_wk + (size_t)DIM * DIM * 2;
  const size_t o_q = o_wv + (size_t)DIM * DIM * 2;
  const size_t o_k = o_q + (size_t)SEQ * DIM * 2;
  const size_t o_vt = o_k + (size_t)SEQ * DIM * 2;
  const size_t o_part = o_vt + (size_t)SEQ * DIM * 2;
  const size_t o_l = o_part + (size_t)2 * SEQ * DIM * 2;   // bf16 partials
  const size_t total_g2 = o_l + (size_t)2 * SEQ * 4;

  unsigned short* Xbf = (unsigned short*)(ws + o_xbf);
  unsigned short* Wqb = (unsigned short*)(ws + o_wq);
  unsigned short* Wkb = (unsigned short*)(ws + o_wk);
  unsigned short* Wvb = (unsigned short*)(ws + o_wv);
  unsigned short* Qb = (unsigned short*)(ws + o_q);
  unsigned short* Kb = (unsigned short*)(ws + o_k);
  unsigned short* Vtb = (unsigned short*)(ws + o_vt);
  unsigned short* part = (unsigned short*)(ws + o_part);
  float* lbuf = (float*)(ws + o_l);

  const int G = (ws_size >= total_g2) ? 2 : 1;

  cast_all_kernel<<<7872, 256, 0, stream>>>(x, wq, wk, wv, Xbf, Wqb, Wkb, Wvb);
  proj_kernel<<<dim3(64, 6, 3), 256, 0, stream>>>(Xbf, Wqb, Wkb, Wvb, Qb, Kb, Vtb);
  if (G == 2) {
    flash_kernel<<<dim3(128, 2), 512, 0, stream>>>(Qb, Kb, Vtb, part, nullptr, lbuf, SEQ / 2, 0);
    combine_kernel<<<6144, 256, 0, stream>>>(part, lbuf, out, SEQ * DIM / 4);
  } else {
    flash_kernel<<<dim3(128, 1), 512, 0, stream>>>(Qb, Kb, Vtb, nullptr, out, nullptr, SEQ, 1);
  }
}